// Round 8
// baseline (288.822 us; speedup 1.0000x reference)
//
#include <hip/hip_runtime.h>
#include <hip/hip_bf16.h>

// ---------------- problem constants ----------------
#define HW    4096      // H*W
#define BB    8         // batch
#define TT    8         // time steps

// ws layout (in floats)
constexpr int OFF_SBUF  = 0;                   // 8*64*4096 = 2097152 floats
constexpr int OFF_WFRAG = 2097152;             // 34 frags * 64 lanes * 16B = 8704 floats
constexpr int OFF_WTOUT = OFF_WFRAG + 8704;    // 4096 floats (Wt_out[c][o])
constexpr int OFF_WXB   = OFF_WTOUT + 4096;    // 256 float2 = 512 floats {w_x, bias}

typedef _Float16 halfx8 __attribute__((ext_vector_type(8)));
typedef float    floatx4 __attribute__((ext_vector_type(4)));
typedef float    floatx2 __attribute__((ext_vector_type(2)));

__device__ inline float fast_exp2(float x) {
#if __has_builtin(__builtin_amdgcn_exp2f)
    return __builtin_amdgcn_exp2f(x);
#else
    return __builtin_exp2f(x);
#endif
}
__device__ inline float fast_rcp(float x) {
#if __has_builtin(__builtin_amdgcn_rcpf)
    return __builtin_amdgcn_rcpf(x);
#else
    return 1.0f / x;
#endif
}
__device__ inline floatx2 exp2x2(floatx2 x) {
    floatx2 r; r.x = fast_exp2(x.x); r.y = fast_exp2(x.y); return r;
}
__device__ inline floatx2 rcpx2(floatx2 x) {
    floatx2 r; r.x = fast_rcp(x.x); r.y = fast_rcp(x.y); return r;
}

union pack8 { _Float16 h[8]; uint4 u; };

// ---------------- prep: repack weights into d_ws (2 blocks) ----------------
__global__ __launch_bounds__(256) void prep_kernel(
    const float* __restrict__ w_ih,  const float* __restrict__ w_hh,
    const float* __restrict__ b_ih,  const float* __restrict__ b_hh,
    const float* __restrict__ w_s,   const float* __restrict__ w_out,
    float* __restrict__ ws_f) {
    int tid = threadIdx.x;
    if (blockIdx.x == 0) {
        // w_hh -> B-fragment-ordered f16. frag fi = nb*2+kc; entry e = fi*64 + lane.
        // lane l holds B[k = kc*32+(l>>4)*8 + j][n=(l&15)]: w_hh[gate=(l&15)+16*nb][hid=k]
        uint4* wf = (uint4*)(ws_f + OFF_WFRAG);
        #pragma unroll
        for (int i = 0; i < 8; ++i) {
            int e  = tid + 256 * i;
            int l  = e & 63;
            int fi = e >> 6;
            int nb = fi >> 1, kc = fi & 1;
            int gate = (l & 15) + 16 * nb;
            int hid  = kc * 32 + (l >> 4) * 8;
            const float* src = w_hh + gate * 64 + hid;
            pack8 p;
            #pragma unroll
            for (int j = 0; j < 8; ++j) p.h[j] = (_Float16)src[j];
            wf[e] = p.u;
        }
        // s-projection fragments (frags 32,33): B[k][0] = w_s[k], other cols 0
        if (tid < 128) {
            int l = tid & 63, kc = tid >> 6;
            pack8 p;
            #pragma unroll
            for (int j = 0; j < 8; ++j) p.h[j] = (_Float16)0.0f;
            if ((l & 15) == 0) {
                #pragma unroll
                for (int j = 0; j < 8; ++j)
                    p.h[j] = (_Float16)w_s[kc * 32 + (l >> 4) * 8 + j];
            }
            wf[2048 + kc * 64 + l] = p.u;
        }
    } else {
        // transposed conv-out weights: Wt[c][o] = w_out[o][c]
        #pragma unroll
        for (int i = 0; i < 16; ++i) {
            int idx = tid + 256 * i;
            int o = idx & 63, c = idx >> 6;
            ws_f[OFF_WTOUT + idx] = w_out[o * 64 + c];
        }
        // {w_x, bias} pairs
        floatx2* wxb = (floatx2*)(ws_f + OFF_WXB);
        floatx2 v; v.x = w_ih[tid]; v.y = b_ih[tid] + b_hh[tid];
        wxb[tid] = v;
    }
}

// ---------------- fused conv_in + per-pixel LSTM ----------------
// 512-thread blocks, 70KB LDS -> 2 blocks/CU, 16 waves/CU (r7: 189us at
// VGPR=52, VALUBusy 72%). The asm memory barrier keeps B-frags in LDS
// (VGPR low); wxb and the batched-rcp activations spend the 76-reg slack
// on fewer LDS reads and fewer trans ops. MUST stay VGPR<=128 (2-block cliff).
// NO forced min-waves bound (r2/r3: arch/AGPR split + spills).
__global__ __launch_bounds__(512) void lstm_kernel(
    const float* __restrict__ hin,    // (B, 64, HW) original input h
    const float* __restrict__ ws_f,   // tables
    float* __restrict__ s_buf,        // (B, 64, HW) output s values
    const float* __restrict__ w_in,   // (64, 64)
    const float* __restrict__ b_in,   // (64,)
    const float* __restrict__ b_s_p) {
    __shared__ uint4 wfrag_lds[2176];                  // 34816 B
    __shared__ floatx2 wxb_lds[256];                   // 2048 B
    __shared__ floatx2 w8p[256];                       // 2048 B
    __shared__ __align__(16) unsigned char uni[32768]; // h_stage 32KB / x(4KB)+h_lds(18KB)
    float*    h_stage = (float*)uni;                   // 64 ch x 128 px fp32
    float*    x_lds   = (float*)uni;                   // 8 t x 128 px fp32 (bytes 0..4096)
    _Float16* h_lds   = (_Float16*)(uni + 4096);       // 8 waves x 16 x 72 f16 (18432 B)

    int tid = threadIdx.x;
    int bg    = blockIdx.x & 63;          // b*8+g (64 consecutive blocks share a pixel tile)
    int ptile = blockIdx.x >> 6;          // 0..31
    int b = bg >> 3, g = bg & 7;
    int p0 = ptile * 128;

    int lane = tid & 63;
    int wv   = tid >> 6;                  // 0..7
    int s    = lane & 15;
    int q    = lane >> 4;

    // stage weight fragments (shared by all 8 waves)
    const uint4* wfg = (const uint4*)(ws_f + OFF_WFRAG);
    #pragma unroll
    for (int i = 0; i < 5; ++i) {
        int e = tid + 512 * i;
        if (e < 2176) wfrag_lds[e] = wfg[e];
    }
    if (tid < 256) {
        // per-gate {w_x, bias}
        wxb_lds[tid] = ((const floatx2*)(ws_f + OFF_WXB))[tid];
        // conv-in weight pairs: e = c*4+tq
        int c = tid >> 2, tq_ = tid & 3;
        floatx2 v;
        v.x = w_in[(g * 8 + tq_) * 64 + c];
        v.y = w_in[(g * 8 + tq_ + 4) * 64 + c];
        w8p[tid] = v;
    }

    // ---- stage hin tile: 64 ch x 128 px ----
    #pragma unroll
    for (int i = 0; i < 4; ++i) {
        int e  = tid + 512 * i;            // 2048 float4
        int cc = e >> 5, f4 = e & 31;
        ((floatx4*)h_stage)[e] = *(const floatx4*)&hin[(b * 64 + cc) * HW + p0 + f4 * 4];
    }
    __syncthreads();

    // ---- fused conv_in: x[t][px] = sum_c w_in[g*8+t][c]*hin[b][c][p0+px] + b_in ----
    int px = tid & 127, tq = tid >> 7;     // outputs (t=tq, t=tq+4) for pixel px
    floatx2 xacc; xacc.x = b_in[g * 8 + tq]; xacc.y = b_in[g * 8 + tq + 4];
    #pragma unroll 8
    for (int cc = 0; cc < 64; ++cc) {
        float hv = h_stage[cc * 128 + px];
        floatx2 w = w8p[cc * 4 + tq];
        floatx2 h2; h2.x = hv; h2.y = hv;
        xacc = xacc + w * h2;
    }
    __syncthreads();                       // all h_stage reads done
    x_lds[tq * 128 + px]       = xacc.x;
    x_lds[(tq + 4) * 128 + px] = xacc.y;
    // zero h state (bytes 4096..22528 of uni)
    #pragma unroll
    for (int i = 0; i < 9; ++i)
        ((unsigned*)(uni + 4096))[tid + 512 * i] = 0u;
    __syncthreads();

    // pre-load {w_x, bias} into registers (constant-indexed -> scalarized;
    // the memory clobber below cannot evict SSA register values)
    floatx2 wxb_r[16];
    #pragma unroll
    for (int nb = 0; nb < 16; ++nb) wxb_r[nb] = wxb_lds[s + 16 * nb];

    _Float16* hrow = h_lds + wv * 16 * 72;
    int pw = p0 + wv * 16;
    float bs = b_s_p[0];

    const float KS = -1.44269504088896f;  // sigmoid: 1/(1+2^(KS*x))
    const float KT =  2.88539008177793f;  // tanh: 1 - 2/(2^(KT*x)+1)

    float c_st[4][4];
    #pragma unroll
    for (int hb = 0; hb < 4; ++hb)
        #pragma unroll
        for (int r = 0; r < 4; ++r) c_st[hb][r] = 0.0f;

    for (int t = 0; t < TT; ++t) {
        // Hard memory barrier: forbids caching LDS B-frags in registers
        // across iterations (r7: this is what keeps VGPR low -> 16 waves/CU).
        asm volatile("" ::: "memory");

        halfx8 a0 = *(const halfx8*)(hrow + s * 72 + q * 8);        // k = 0..31
        halfx8 a1 = *(const halfx8*)(hrow + s * 72 + q * 8 + 32);   // k = 32..63

        // s_{t-1} = h_t @ w_s via MFMA (col 0 only); lanes s==0 hold seq q*4+r
        if (t > 0) {
            halfx8 sb0 = *(const halfx8*)&wfrag_lds[32 * 64 + lane];
            halfx8 sb1 = *(const halfx8*)&wfrag_lds[33 * 64 + lane];
            floatx4 sa = {0.f, 0.f, 0.f, 0.f};
            sa = __builtin_amdgcn_mfma_f32_16x16x32_f16(a0, sb0, sa, 0, 0, 0);
            sa = __builtin_amdgcn_mfma_f32_16x16x32_f16(a1, sb1, sa, 0, 0, 0);
            if (s == 0) {
                floatx4 o4 = {sa[0] + bs, sa[1] + bs, sa[2] + bs, sa[3] + bs};
                *(floatx4*)&s_buf[(bg * 8 + (t - 1)) * HW + pw + q * 4] = o4;
            }
        }

        floatx4 xv = *(const floatx4*)&x_lds[t * 128 + wv * 16 + q * 4];
        floatx2 xlo; xlo.x = xv[0]; xlo.y = xv[1];
        floatx2 xhi; xhi.x = xv[2]; xhi.y = xv[3];

        #pragma unroll
        for (int hb = 0; hb < 4; ++hb) {
            floatx4 acc[4];
            #pragma unroll
            for (int gi = 0; gi < 4; ++gi) {
                int nb = hb + 4 * gi;
                floatx2 wb = wxb_r[nb];
                floatx2 lo = xlo * wb.x + wb.y;     // x*w_x + bias as C init (pk_fma)
                floatx2 hi = xhi * wb.x + wb.y;
                floatx4 a = {lo.x, lo.y, hi.x, hi.y};
                halfx8 b0 = *(const halfx8*)&wfrag_lds[(nb * 2 + 0) * 64 + lane];
                halfx8 b1 = *(const halfx8*)&wfrag_lds[(nb * 2 + 1) * 64 + lane];
                a = __builtin_amdgcn_mfma_f32_16x16x32_f16(a0, b0, a, 0, 0, 0);
                a = __builtin_amdgcn_mfma_f32_16x16x32_f16(a1, b1, a, 0, 0, 0);
                acc[gi] = a;
            }
            // ---- activations: batched packed reciprocals (r5 math, verified)
            // rcp count 20 -> 6 scalar per hb; trans unit is ~half of VALU busy.
            #define ACCP(gi, p) (floatx2{acc[gi][2*(p)], acc[gi][2*(p)+1]})
            // group 1: i (sigmoid), f (sigmoid)
            floatx2 dI0 = exp2x2(ACCP(0,0) * KS) + 1.0f;
            floatx2 dI1 = exp2x2(ACCP(0,1) * KS) + 1.0f;
            floatx2 dF0 = exp2x2(ACCP(1,0) * KS) + 1.0f;
            floatx2 dF1 = exp2x2(ACCP(1,1) * KS) + 1.0f;
            floatx2 q1 = dI0 * dI1, q2 = q1 * dF0, q3 = q2 * dF1;
            floatx2 R  = rcpx2(q3);
            floatx2 fg1 = R * q2;  R = R * dF1;
            floatx2 fg0 = R * q1;  R = R * dF0;
            floatx2 ig1 = R * dI0;
            floatx2 ig0 = R * dI1;
            // group 2: g (tanh), o (sigmoid)
            floatx2 dG0 = exp2x2(ACCP(2,0) * KT) + 1.0f;
            floatx2 dG1 = exp2x2(ACCP(2,1) * KT) + 1.0f;
            floatx2 dO0 = exp2x2(ACCP(3,0) * KS) + 1.0f;
            floatx2 dO1 = exp2x2(ACCP(3,1) * KS) + 1.0f;
            q1 = dG0 * dG1; q2 = q1 * dO0; q3 = q2 * dO1;
            R  = rcpx2(q3);
            floatx2 og1 = R * q2;  R = R * dO1;
            floatx2 og0 = R * q1;  R = R * dO0;
            floatx2 gv1 = (R * dG0) * -2.0f + 1.0f;   // tanh(g) pair1
            floatx2 gv0 = (R * dG1) * -2.0f + 1.0f;   // tanh(g) pair0
            // cell update
            floatx2 cp0; cp0.x = c_st[hb][0]; cp0.y = c_st[hb][1];
            floatx2 cp1; cp1.x = c_st[hb][2]; cp1.y = c_st[hb][3];
            floatx2 c0 = fg0 * cp0 + ig0 * gv0;
            floatx2 c1 = fg1 * cp1 + ig1 * gv1;
            c_st[hb][0] = c0.x; c_st[hb][1] = c0.y;
            c_st[hb][2] = c1.x; c_st[hb][3] = c1.y;
            // tanh(c), batched
            floatx2 dc0 = exp2x2(c0 * KT) + 1.0f;
            floatx2 dc1 = exp2x2(c1 * KT) + 1.0f;
            floatx2 qc = dc0 * dc1;
            floatx2 Rc = rcpx2(qc);
            floatx2 h1 = og1 * ((Rc * dc0) * -2.0f + 1.0f);
            floatx2 h0 = og0 * ((Rc * dc1) * -2.0f + 1.0f);
            // store h (f16) for t+1
            _Float16* wp = hrow + (q * 4) * 72 + s + 16 * hb;
            wp[0 * 72] = (_Float16)h0.x;
            wp[1 * 72] = (_Float16)h0.y;
            wp[2 * 72] = (_Float16)h1.x;
            wp[3 * 72] = (_Float16)h1.y;
            #undef ACCP
        }
    }
    // final s_7 from h_8
    {
        asm volatile("" ::: "memory");
        halfx8 a0 = *(const halfx8*)(hrow + s * 72 + q * 8);
        halfx8 a1 = *(const halfx8*)(hrow + s * 72 + q * 8 + 32);
        halfx8 sb0 = *(const halfx8*)&wfrag_lds[32 * 64 + lane];
        halfx8 sb1 = *(const halfx8*)&wfrag_lds[33 * 64 + lane];
        floatx4 sa = {0.f, 0.f, 0.f, 0.f};
        sa = __builtin_amdgcn_mfma_f32_16x16x32_f16(a0, sb0, sa, 0, 0, 0);
        sa = __builtin_amdgcn_mfma_f32_16x16x32_f16(a1, sb1, sa, 0, 0, 0);
        if (s == 0) {
            floatx4 o4 = {sa[0] + bs, sa[1] + bs, sa[2] + bs, sa[3] + bs};
            *(floatx4*)&s_buf[(bg * 8 + 7) * HW + pw + q * 4] = o4;
        }
    }
}

// ---------------- conv_out: 1x1 conv, 32 outputs/thread (2x s_buf re-read) ----
__global__ __launch_bounds__(256) void conv_out_kernel(
    const float* __restrict__ x, const float* __restrict__ Wt,
    const float* __restrict__ bias, float* __restrict__ y) {
    int p  = blockIdx.x * 256 + threadIdx.x;
    int b  = blockIdx.y;
    int oh = blockIdx.z;                  // outputs [32*oh, 32*oh+32)
    const float* xb = x + b * 64 * HW;
    const floatx2* Wt2 = (const floatx2*)Wt;  // row c: 32 float2 pairs
    floatx2 acc[16];
    #pragma unroll
    for (int j = 0; j < 16; ++j) { acc[j].x = 0.f; acc[j].y = 0.f; }
    #pragma unroll 4
    for (int c = 0; c < 64; ++c) {
        float hv = xb[c * HW + p];
        floatx2 h2; h2.x = hv; h2.y = hv;
        #pragma unroll
        for (int j = 0; j < 16; ++j)
            acc[j] = acc[j] + Wt2[c * 32 + oh * 16 + j] * h2;
    }
    float* yb = y + b * 64 * HW + oh * 32 * HW;
    #pragma unroll
    for (int j = 0; j < 16; ++j) {
        yb[(2 * j) * HW + p]     = acc[j].x + bias[oh * 32 + 2 * j];
        yb[(2 * j + 1) * HW + p] = acc[j].y + bias[oh * 32 + 2 * j + 1];
    }
}

extern "C" void kernel_launch(void* const* d_in, const int* in_sizes, int n_in,
                              void* d_out, int out_size, void* d_ws, size_t ws_size,
                              hipStream_t stream) {
    const float* h     = (const float*)d_in[0];
    const float* w_in  = (const float*)d_in[1];
    const float* b_in  = (const float*)d_in[2];
    const float* w_ih  = (const float*)d_in[3];
    const float* w_hh  = (const float*)d_in[4];
    const float* b_ih  = (const float*)d_in[5];
    const float* b_hh  = (const float*)d_in[6];
    const float* w_s   = (const float*)d_in[7];
    const float* b_s   = (const float*)d_in[8];
    const float* w_out = (const float*)d_in[9];
    const float* b_out = (const float*)d_in[10];
    float* out = (float*)d_out;
    float* ws  = (float*)d_ws;

    prep_kernel<<<2, 256, 0, stream>>>(w_ih, w_hh, b_ih, b_hh, w_s, w_out, ws);
    // fused conv_in + LSTM: hin -> s_buf (ws). 2048 blocks x 512 threads.
    lstm_kernel<<<2048, 512, 0, stream>>>(h, ws, ws + OFF_SBUF, w_in, b_in, b_s);
    // conv_out: s_buf -> d_out
    conv_out_kernel<<<dim3(16, BB, 2), 256, 0, stream>>>(ws + OFF_SBUF, ws + OFF_WTOUT, b_out, out);
}

// Round 9
// 244.820 us; speedup vs baseline: 1.1797x; 1.1797x over previous
//
#include <hip/hip_runtime.h>
#include <hip/hip_bf16.h>

// ---------------- problem constants ----------------
#define HW    4096      // H*W
#define BB    8         // batch
#define TT    8         // time steps

// ws layout (in floats)
constexpr int OFF_WFRAG = 0;                   // 34 frags * 64 lanes * 16B = 8704 floats
constexpr int OFF_WTOUT = OFF_WFRAG + 8704;    // 4096 floats (Wt_out[c][o])
constexpr int OFF_WXB   = OFF_WTOUT + 4096;    // 256 float2 = 512 floats {w_x, bias}

typedef _Float16 halfx8 __attribute__((ext_vector_type(8)));
typedef float    floatx4 __attribute__((ext_vector_type(4)));
typedef float    floatx2 __attribute__((ext_vector_type(2)));

__device__ inline float fast_exp2(float x) {
#if __has_builtin(__builtin_amdgcn_exp2f)
    return __builtin_amdgcn_exp2f(x);
#else
    return __builtin_exp2f(x);
#endif
}
__device__ inline float fast_rcp(float x) {
#if __has_builtin(__builtin_amdgcn_rcpf)
    return __builtin_amdgcn_rcpf(x);
#else
    return 1.0f / x;
#endif
}
__device__ inline floatx2 exp2x2(floatx2 x) {
    floatx2 r; r.x = fast_exp2(x.x); r.y = fast_exp2(x.y); return r;
}
__device__ inline floatx2 rcpx2(floatx2 x) {
    floatx2 r; r.x = fast_rcp(x.x); r.y = fast_rcp(x.y); return r;
}
__device__ inline floatx2 fsig2(floatx2 x) {          // sigmoid
    return rcpx2(exp2x2(x * -1.44269504088896f) + 1.0f);
}
__device__ inline floatx2 ftanh2(floatx2 x) {         // tanh
    floatx2 r = rcpx2(exp2x2(x * 2.88539008177793f) + 1.0f);
    return r * -2.0f + 1.0f;
}

union pack8 { _Float16 h[8]; uint4 u; };

// ---------------- prep: repack weights into d_ws (2 blocks) ----------------
__global__ __launch_bounds__(256) void prep_kernel(
    const float* __restrict__ w_ih,  const float* __restrict__ w_hh,
    const float* __restrict__ b_ih,  const float* __restrict__ b_hh,
    const float* __restrict__ w_s,   const float* __restrict__ w_out,
    float* __restrict__ ws_f) {
    int tid = threadIdx.x;
    if (blockIdx.x == 0) {
        // w_hh -> B-fragment-ordered f16. frag fi = nb*2+kc; entry e = fi*64 + lane.
        // lane l holds B[k = kc*32+(l>>4)*8 + j][n=(l&15)]: w_hh[gate=(l&15)+16*nb][hid=k]
        uint4* wf = (uint4*)(ws_f + OFF_WFRAG);
        #pragma unroll
        for (int i = 0; i < 8; ++i) {
            int e  = tid + 256 * i;
            int l  = e & 63;
            int fi = e >> 6;
            int nb = fi >> 1, kc = fi & 1;
            int gate = (l & 15) + 16 * nb;
            int hid  = kc * 32 + (l >> 4) * 8;
            const float* src = w_hh + gate * 64 + hid;
            pack8 p;
            #pragma unroll
            for (int j = 0; j < 8; ++j) p.h[j] = (_Float16)src[j];
            wf[e] = p.u;
        }
        // s-projection fragments (frags 32,33): B[k][0] = w_s[k], other cols 0
        if (tid < 128) {
            int l = tid & 63, kc = tid >> 6;
            pack8 p;
            #pragma unroll
            for (int j = 0; j < 8; ++j) p.h[j] = (_Float16)0.0f;
            if ((l & 15) == 0) {
                #pragma unroll
                for (int j = 0; j < 8; ++j)
                    p.h[j] = (_Float16)w_s[kc * 32 + (l >> 4) * 8 + j];
            }
            wf[2048 + kc * 64 + l] = p.u;
        }
    } else {
        // transposed conv-out weights: Wt[c][o] = w_out[o][c]
        #pragma unroll
        for (int i = 0; i < 16; ++i) {
            int idx = tid + 256 * i;
            int o = idx & 63, c = idx >> 6;
            ws_f[OFF_WTOUT + idx] = w_out[o * 64 + c];
        }
        // {w_x, bias} pairs
        floatx2* wxb = (floatx2*)(ws_f + OFF_WXB);
        floatx2 v; v.x = w_ih[tid]; v.y = b_ih[tid] + b_hh[tid];
        wxb[tid] = v;
    }
}

// ---------------- fully fused conv_in + LSTM + conv_out ----------------
// Block = 512 threads = 8 waves = ONE 16-pixel tile x ALL 8 groups (wave wv
// handles group g=wv). All 64 s-channels of the tile stay block-resident in
// LDS -> no s_buf global round-trip, no second GEMM kernel, hin tiles are
// block-private (FETCH 33 -> ~10 MB).
// t-loop is r7-verbatim: asm memory barrier keeps B-frags in LDS (VGPR=52,
// 2 blocks/CU, 16 waves/CU). r8 lesson: wxb-in-regs / batched-rcp push the
// unified VGPR+AGPR total over the 4-waves/SIMD cliff -> reverted.
// LDS = 79872 B <= 81920 -> 2 blocks/CU. NO forced min-waves bound (r2/r3).
__global__ __launch_bounds__(512) void lstm_kernel(
    const float* __restrict__ hin,    // (B, 64, HW) original input h
    const float* __restrict__ ws_f,   // tables
    float* __restrict__ out,          // (B, 64, HW) final output
    const float* __restrict__ w_in,   // (64, 64)
    const float* __restrict__ b_in,   // (64,)
    const float* __restrict__ b_s_p,  // (1,)
    const float* __restrict__ b_out) {// (64,)
    __shared__ uint4 wfrag_lds[2176];                  // 34816 B
    __shared__ floatx2 wxb_lds[256];                   // 2048 B
    __shared__ __align__(16) float x_lds[1024];        // 4096 B: [g][t][px16]
    __shared__ __align__(16) _Float16 h_lds[9216];     // 18432 B: 8 waves x 16 x 72
    __shared__ __align__(16) float stile[1024];        // 4096 B: [c64][px16]; aliases hin staging
    __shared__ __align__(16) float wt_lds[4096];       // 16384 B: w_in, then Wt_out

    int tid = threadIdx.x;
    int ptile = blockIdx.x & 255;         // 256 tiles of 16 px
    int b     = blockIdx.x >> 8;
    int p0 = ptile * 16;

    int lane = tid & 63;
    int wv   = tid >> 6;                  // 0..7 == group g
    int g    = wv;
    int s    = lane & 15;                 // seq-local == pixel-local
    int q    = lane >> 4;

    // stage weight fragments (shared by all 8 waves)
    const uint4* wfg = (const uint4*)(ws_f + OFF_WFRAG);
    #pragma unroll
    for (int i = 0; i < 5; ++i) {
        int e = tid + 512 * i;
        if (e < 2176) wfrag_lds[e] = wfg[e];
    }
    if (tid < 256) wxb_lds[tid] = ((const floatx2*)(ws_f + OFF_WXB))[tid];
    // stage w_in (identity copy, [o][c] row-major) into wt_lds
    #pragma unroll
    for (int i = 0; i < 2; ++i)
        ((floatx4*)wt_lds)[tid + 512 * i] = ((const floatx4*)w_in)[tid + 512 * i];
    // stage hin tile (64 ch x 16 px) into stile (aliased)
    if (tid < 256) {
        int cc = tid >> 2, f4 = tid & 3;
        ((floatx4*)stile)[tid] = *(const floatx4*)&hin[(b * 64 + cc) * HW + p0 + f4 * 4];
    }
    __syncthreads();

    // ---- conv_in (per wave, own group): x[g][t][px] = sum_c w_in[g8+t][c]*hin[c][px] + b_in
    {
        floatx2 xacc; xacc.x = b_in[g * 8 + q]; xacc.y = b_in[g * 8 + q + 4];
        #pragma unroll 8
        for (int cc = 0; cc < 64; ++cc) {
            float hv = stile[cc * 16 + s];
            floatx2 w;
            w.x = wt_lds[(g * 8 + q) * 64 + cc];
            w.y = wt_lds[(g * 8 + q + 4) * 64 + cc];
            floatx2 h2; h2.x = hv; h2.y = hv;
            xacc = xacc + w * h2;
        }
        x_lds[g * 128 + q * 16 + s]       = xacc.x;
        x_lds[g * 128 + (q + 4) * 16 + s] = xacc.y;
    }
    // zero h state (4608 u32)
    #pragma unroll
    for (int i = 0; i < 9; ++i)
        ((unsigned*)h_lds)[tid + 512 * i] = 0u;
    __syncthreads();   // hin/w_in reads + x/h writes complete

    // stage Wt_out ([c][o]) into wt_lds for the epilogue (read after next barrier)
    #pragma unroll
    for (int i = 0; i < 2; ++i)
        ((floatx4*)wt_lds)[tid + 512 * i] =
            ((const floatx4*)(ws_f + OFF_WTOUT))[tid + 512 * i];

    _Float16* hrow = h_lds + wv * 16 * 72;
    float bs = b_s_p[0];

    float c_st[4][4];
    #pragma unroll
    for (int hb = 0; hb < 4; ++hb)
        #pragma unroll
        for (int r = 0; r < 4; ++r) c_st[hb][r] = 0.0f;

    for (int t = 0; t < TT; ++t) {
        // Hard memory barrier: forbids caching LDS B-frags in registers
        // across iterations (r7: this is what keeps VGPR low -> 16 waves/CU).
        asm volatile("" ::: "memory");

        halfx8 a0 = *(const halfx8*)(hrow + s * 72 + q * 8);        // k = 0..31
        halfx8 a1 = *(const halfx8*)(hrow + s * 72 + q * 8 + 32);   // k = 32..63

        // s_{t-1} = h_t @ w_s via MFMA (col 0 only); lanes s==0 hold seq q*4+r
        if (t > 0) {
            halfx8 sb0 = *(const halfx8*)&wfrag_lds[32 * 64 + lane];
            halfx8 sb1 = *(const halfx8*)&wfrag_lds[33 * 64 + lane];
            floatx4 sa = {0.f, 0.f, 0.f, 0.f};
            sa = __builtin_amdgcn_mfma_f32_16x16x32_f16(a0, sb0, sa, 0, 0, 0);
            sa = __builtin_amdgcn_mfma_f32_16x16x32_f16(a1, sb1, sa, 0, 0, 0);
            if (s == 0) {
                floatx4 o4 = {sa[0] + bs, sa[1] + bs, sa[2] + bs, sa[3] + bs};
                *(floatx4*)&stile[(g * 8 + (t - 1)) * 16 + q * 4] = o4;
            }
        }

        floatx4 xv = *(const floatx4*)&x_lds[g * 128 + t * 16 + q * 4];
        floatx2 xlo; xlo.x = xv[0]; xlo.y = xv[1];
        floatx2 xhi; xhi.x = xv[2]; xhi.y = xv[3];

        #pragma unroll
        for (int hb = 0; hb < 4; ++hb) {
            floatx4 acc[4];
            #pragma unroll
            for (int gi = 0; gi < 4; ++gi) {
                int nb = hb + 4 * gi;
                floatx2 wb = wxb_lds[s + 16 * nb];
                floatx2 lo = xlo * wb.x + wb.y;     // x*w_x + bias as C init (pk_fma)
                floatx2 hi = xhi * wb.x + wb.y;
                floatx4 a = {lo.x, lo.y, hi.x, hi.y};
                halfx8 b0 = *(const halfx8*)&wfrag_lds[(nb * 2 + 0) * 64 + lane];
                halfx8 b1 = *(const halfx8*)&wfrag_lds[(nb * 2 + 1) * 64 + lane];
                a = __builtin_amdgcn_mfma_f32_16x16x32_f16(a0, b0, a, 0, 0, 0);
                a = __builtin_amdgcn_mfma_f32_16x16x32_f16(a1, b1, a, 0, 0, 0);
                acc[gi] = a;
            }
            int s16 = s + 16 * hb;
            _Float16* wp = hrow + (q * 4) * 72 + s16;
            #pragma unroll
            for (int p = 0; p < 2; ++p) {
                int r0 = 2 * p;
                floatx2 iv; iv.x = acc[0][r0]; iv.y = acc[0][r0 + 1]; iv = fsig2(iv);
                floatx2 fv; fv.x = acc[1][r0]; fv.y = acc[1][r0 + 1]; fv = fsig2(fv);
                floatx2 gv; gv.x = acc[2][r0]; gv.y = acc[2][r0 + 1]; gv = ftanh2(gv);
                floatx2 ov; ov.x = acc[3][r0]; ov.y = acc[3][r0 + 1]; ov = fsig2(ov);
                floatx2 cp; cp.x = c_st[hb][r0]; cp.y = c_st[hb][r0 + 1];
                floatx2 c = fv * cp + iv * gv;
                c_st[hb][r0] = c.x; c_st[hb][r0 + 1] = c.y;
                floatx2 hn = ov * ftanh2(c);
                wp[(r0 + 0) * 72] = (_Float16)hn.x;   // state for t+1
                wp[(r0 + 1) * 72] = (_Float16)hn.y;
            }
        }
    }
    // final s_7 from h_8
    {
        asm volatile("" ::: "memory");
        halfx8 a0 = *(const halfx8*)(hrow + s * 72 + q * 8);
        halfx8 a1 = *(const halfx8*)(hrow + s * 72 + q * 8 + 32);
        halfx8 sb0 = *(const halfx8*)&wfrag_lds[32 * 64 + lane];
        halfx8 sb1 = *(const halfx8*)&wfrag_lds[33 * 64 + lane];
        floatx4 sa = {0.f, 0.f, 0.f, 0.f};
        sa = __builtin_amdgcn_mfma_f32_16x16x32_f16(a0, sb0, sa, 0, 0, 0);
        sa = __builtin_amdgcn_mfma_f32_16x16x32_f16(a1, sb1, sa, 0, 0, 0);
        if (s == 0) {
            floatx4 o4 = {sa[0] + bs, sa[1] + bs, sa[2] + bs, sa[3] + bs};
            *(floatx4*)&stile[(g * 8 + 7) * 16 + q * 4] = o4;
        }
    }
    __syncthreads();   // stile (all 64 channels) + wt_lds (Wt_out) ready

    // ---- conv_out epilogue: out[b][o][p0+px] = sum_c Wt_out[c][o]*stile[c][px] + b_out[o]
    {
        int px = tid & 15;
        int oo = tid >> 4;                 // 0..31 -> outputs oo and oo+32
        floatx2 acc; acc.x = b_out[oo]; acc.y = b_out[oo + 32];
        #pragma unroll 8
        for (int c = 0; c < 64; ++c) {
            float sv = stile[c * 16 + px];
            floatx2 w;
            w.x = wt_lds[c * 64 + oo];
            w.y = wt_lds[c * 64 + oo + 32];
            floatx2 s2; s2.x = sv; s2.y = sv;
            acc = acc + w * s2;
        }
        out[(b * 64 + oo) * HW + p0 + px]      = acc.x;
        out[(b * 64 + oo + 32) * HW + p0 + px] = acc.y;
    }
}

extern "C" void kernel_launch(void* const* d_in, const int* in_sizes, int n_in,
                              void* d_out, int out_size, void* d_ws, size_t ws_size,
                              hipStream_t stream) {
    const float* h     = (const float*)d_in[0];
    const float* w_in  = (const float*)d_in[1];
    const float* b_in  = (const float*)d_in[2];
    const float* w_ih  = (const float*)d_in[3];
    const float* w_hh  = (const float*)d_in[4];
    const float* b_ih  = (const float*)d_in[5];
    const float* b_hh  = (const float*)d_in[6];
    const float* w_s   = (const float*)d_in[7];
    const float* b_s   = (const float*)d_in[8];
    const float* w_out = (const float*)d_in[9];
    const float* b_out = (const float*)d_in[10];
    float* out = (float*)d_out;
    float* ws  = (float*)d_ws;

    prep_kernel<<<2, 256, 0, stream>>>(w_ih, w_hh, b_ih, b_hh, w_s, w_out, ws);
    // fully fused conv_in + LSTM + conv_out: hin -> out. 2048 blocks x 512 threads.
    lstm_kernel<<<2048, 512, 0, stream>>>(h, ws, out, w_in, b_in, b_s, b_out);
}